// Round 13
// baseline (613.263 us; speedup 1.0000x reference)
//
#include <hip/hip_runtime.h>
#include <math.h>

#define BTOT 16384

typedef __attribute__((ext_vector_type(8))) short s16x8;
typedef __attribute__((ext_vector_type(4))) float f32x4;
typedef __attribute__((ext_vector_type(4))) uint u32x4;
typedef __attribute__((ext_vector_type(2))) float f32x2;
typedef __attribute__((ext_vector_type(2))) uint u32x2;

// U region offsets (in ushorts). Per-node blob: [KTN*512 hi][KTN*512 lo].
#define OFF0 0u          // W0: 128 nodes x 5120
#define OFF1 655360u     // W1: 64 x 8192
#define OFF2 1179648u    // W2: 32 x 8192
#define OFF3 1441792u    // W3: 16 x 8192
#define OFF4 1572864u    // W4: 8 x 8192
#define OFF5 1638400u    // W5: 4 x 8192
#define OFF6 1671168u    // W6: 2 x 8192
#define OFF7 1687552u    // W7: 1 x 8192

__device__ __forceinline__ ushort rtn_bf16(float x) {
  uint u = __builtin_bit_cast(uint, x);
  uint r = u + 0x7fffu + ((u >> 16) & 1u);
  return (ushort)(r >> 16);
}

// ---------------- W-frag prep (LDS-staged) + cnt zeroing -----------------------
__global__ __launch_bounds__(256) void wprep_kernel(
    const float* __restrict__ W0, const float* __restrict__ W1,
    const float* __restrict__ W2, const float* __restrict__ W3,
    const float* __restrict__ W4, const float* __restrict__ W5,
    const float* __restrict__ W6, const float* __restrict__ W7,
    ushort* __restrict__ U, uint* __restrict__ cnt) {
  __shared__ float WL[4096];
  int blk = blockIdx.x;
  if (blk == 0) cnt[threadIdx.x] = 0;   // zero epilogue tickets (ws is poisoned)
  const float* Wsrc; ushort* dst; int ktN, din, nsrc; bool dout1 = false;
  if (blk < 128)      { Wsrc = W0 + blk * 1296;         dst = U + OFF0 + (size_t)blk * 5120;         ktN = 5; din = 9;  nsrc = 1296; }
  else if (blk < 192) { Wsrc = W1 + (blk - 128) * 4096; dst = U + OFF1 + (size_t)(blk - 128) * 8192; ktN = 8; din = 16; nsrc = 4096; }
  else if (blk < 224) { Wsrc = W2 + (blk - 192) * 4096; dst = U + OFF2 + (size_t)(blk - 192) * 8192; ktN = 8; din = 16; nsrc = 4096; }
  else if (blk < 240) { Wsrc = W3 + (blk - 224) * 4096; dst = U + OFF3 + (size_t)(blk - 224) * 8192; ktN = 8; din = 16; nsrc = 4096; }
  else if (blk < 248) { Wsrc = W4 + (blk - 240) * 4096; dst = U + OFF4 + (size_t)(blk - 240) * 8192; ktN = 8; din = 16; nsrc = 4096; }
  else if (blk < 252) { Wsrc = W5 + (blk - 248) * 4096; dst = U + OFF5 + (size_t)(blk - 248) * 8192; ktN = 8; din = 16; nsrc = 4096; }
  else if (blk < 254) { Wsrc = W6 + (blk - 252) * 4096; dst = U + OFF6 + (size_t)(blk - 252) * 8192; ktN = 8; din = 16; nsrc = 4096; }
  else                { Wsrc = W7;                      dst = U + OFF7;                              ktN = 8; din = 16; nsrc = 256; dout1 = true; }
  for (int i = threadIdx.x; i < nsrc; i += 256) WL[i] = Wsrc[i];   // coalesced
  __syncthreads();
  int entries = ktN * 512;
  for (int e = threadIdx.x; e < entries; e += 256) {
    int kt = e >> 9, l = (e >> 3) & 63, jv = e & 7;
    int k = kt * 32 + ((l >> 4) << 3) + jv;
    int i = k >> 4, j = k & 15, n = l & 15;
    float w;
    if (dout1) w = (n == 0) ? WL[i * 16 + j] : 0.f;
    else       w = (i < din && j < din) ? WL[(i * din + j) * 16 + n] : 0.f;
    uint u = __builtin_bit_cast(uint, w);
    uint h = u & 0xffff0000u;
    dst[e] = (ushort)(h >> 16);
    dst[entries + e] = rtn_bf16(w - __builtin_bit_cast(float, h));
  }
}

// ---- split + 3 MFMAs for one 16-b tile, given resident wh/wl ------------------
__device__ __forceinline__ f32x4 split3(float li, const f32x2* rf2,
                                        s16x8 wh, s16x8 wl, f32x4 acc) {
  const f32x2 li2 = {li, li};
  u32x4 hv, lv;
#pragma unroll
  for (int jp = 0; jp < 4; ++jp) {
    f32x2 p2 = li2 * rf2[jp];
    u32x2 u2 = __builtin_bit_cast(u32x2, p2);
    u32x2 hb = u2 & 0xffff0000u;
    f32x2 h2 = __builtin_bit_cast(f32x2, hb);
    f32x2 q2 = __builtin_elementwise_fma(li2, rf2[jp], -h2);
    u32x2 uq = __builtin_bit_cast(u32x2, q2);
    hv[jp] = __builtin_amdgcn_perm(u2.y, u2.x, 0x07060302u);
    lv[jp] = __builtin_amdgcn_perm(uq.y, uq.x, 0x07060302u);
  }
  s16x8 ahi = __builtin_bit_cast(s16x8, hv);
  s16x8 alo = __builtin_bit_cast(s16x8, lv);
  acc = __builtin_amdgcn_mfma_f32_16x16x32_bf16(ahi, wh, acc, 0, 0, 0);
  acc = __builtin_amdgcn_mfma_f32_16x16x32_bf16(alo, wh, acc, 0, 0, 0);
  acc = __builtin_amdgcn_mfma_f32_16x16x32_bf16(ahi, wl, acc, 0, 0, 0);
  return acc;
}

// ---------------- single-tile MFMA bilinear core (verified) --------------------
template <int KTN, bool L0M>
__device__ __forceinline__ f32x4 mfma_core(const float* Lcol, const float* Rcol,
                                           const int ld, const ushort* __restrict__ Wf,
                                           int lane) {
  const int g = lane >> 4;
  const int j0 = (g & 1) * 8, gh = g >> 1;
  const float* Lg = Lcol + gh * ld;
  float lf[KTN];
#pragma unroll
  for (int i = 0; i < KTN; ++i)
    lf[i] = (L0M && (2 * i + gh > 8)) ? 0.f : Lg[2 * i * ld];
  f32x2 rf2[4];
#pragma unroll
  for (int j = 0; j < 8; ++j) {
    float v = (L0M && (j0 + j >= 9)) ? 0.f : Rcol[(j0 + j) * ld];
    rf2[j >> 1][j & 1] = v;
  }
  f32x4 acc = {0.f, 0.f, 0.f, 0.f};
  const int entries = KTN * 512;
#pragma unroll
  for (int kt = 0; kt < KTN; ++kt) {
    const s16x8 wh = *(const s16x8*)&Wf[(kt * 64 + lane) * 8];
    const s16x8 wl = *(const s16x8*)&Wf[entries + (kt * 64 + lane) * 8];
    acc = split3(lf[kt], rf2, wh, wl, acc);
  }
  return acc;
}

#define LDF 67   // front leading dim: 67 % 32 = 3 -> <=2-way LDS conflicts (free)

__device__ __forceinline__ void feats_col(float xv, float* Fb, int col) {
  float s1 = __sinf(xv), c1 = __cosf(xv);
  Fb[0 * LDF + col] = 1.f; Fb[1 * LDF + col] = s1; Fb[5 * LDF + col] = c1;
  float sk = s1, ck = c1;
#pragma unroll
  for (int k = 2; k <= 4; ++k) {
    float sn = s1 * ck + c1 * sk, cn = c1 * ck - s1 * sk;
    sk = sn; ck = cn;
    Fb[k * LDF + col] = sk; Fb[(4 + k) * LDF + col] = ck;
  }
}

// ---------------- Fused: levels 0-3 (front) + 4-7 (atomic-ticket epilogue) -----
// Front part = R7/R10/R12 best shape (zero-barrier, 256 thr / 64 b / subtree s).
// After s1 slice written: fence + ticket; 16th arriver for its bblk runs levels
// 4-7 for its 64 b (one 16-b subtile per wave, wave-private, in reused LDS).
__global__ __launch_bounds__(256, 4) void ttn_fused_kernel(
    const float* __restrict__ x, const float* __restrict__ fminp,
    const ushort* __restrict__ U, float* __restrict__ s1out,
    uint* __restrict__ cnt, float* __restrict__ out) {
  __shared__ float LB[7638];   // front: F0,F1,A0,B0,A1,B1,A2,B2 | epilogue: 4x1632
  __shared__ int isLastS;
  float* F0 = LB;            float* F1 = LB + 603;
  float* A0 = LB + 1206;     float* B0 = LB + 2278;
  float* A1 = LB + 3350;     float* B1 = LB + 4422;
  float* A2 = LB + 5494;     float* B2 = LB + 6566;

  const int tid = threadIdx.x;
  const int lane = tid & 63, w = tid >> 6;
  const int m = lane & 15, g = lane >> 4;
  const int bl = w * 16 + m;
  const int bblk = blockIdx.x;
  const int b0 = bblk * 64;
  const int s = blockIdx.y;
  const float fmin = fminp[0];

  const float* xw = x + (size_t)(b0 + w * 16 + (lane & 15)) * 256 + s * 16;
  float* outG = s1out + (size_t)(s * 16) * BTOT + b0;

  auto storeL = [&](f32x4 a, float* Out) {
#pragma unroll
    for (int r = 0; r < 4; ++r) Out[m * LDF + w * 16 + g * 4 + r] = a[r];
  };

  for (int t = 0; t < 8; ++t) {
    if (lane < 32) {
      int side = lane >> 4;
      float xv = xw[2 * t + side] * fmin;
      feats_col(xv, side ? F1 : F0, w * 16 + (lane & 15));
    }
    f32x4 a = mfma_core<5, true>(&F0[bl], &F1[bl], LDF,
                                 U + OFF0 + (size_t)(8 * s + t) * 5120, lane);
    storeL(a, (t & 1) ? B0 : A0);
    if (t & 1) {
      f32x4 c1 = mfma_core<8, false>(&A0[bl], &B0[bl], LDF,
                                     U + OFF1 + (size_t)(4 * s + (t >> 1)) * 8192, lane);
      storeL(c1, ((t >> 1) & 1) ? B1 : A1);
      if ((t & 3) == 3) {
        f32x4 c2 = mfma_core<8, false>(&A1[bl], &B1[bl], LDF,
                                       U + OFF2 + (size_t)(2 * s + (t >> 2)) * 8192, lane);
        storeL(c2, ((t >> 2) & 1) ? B2 : A2);
        if (t == 7) {
          f32x4 c3 = mfma_core<8, false>(&A2[bl], &B2[bl], LDF,
                                         U + OFF3 + (size_t)s * 8192, lane);
#pragma unroll
          for (int r = 0; r < 4; ++r)
            outG[(size_t)m * BTOT + w * 16 + g * 4 + r] = c3[r];
        }
      }
    }
  }

  // ---- epilogue ticket: 16th (s-)arriver for this bblk runs levels 4-7 -------
  __threadfence();                       // release this block's s1 writes
  __syncthreads();
  if (tid == 0) isLastS = (atomicAdd(&cnt[bblk], 1u) == 15u);
  __syncthreads();
  if (!isLastS) return;
  __threadfence();                       // acquire the other 15 blocks' s1

  // wave w owns b-subtile bb = b0 + 16w; wave-private chain, zero barriers.
  const float* s1r = s1out + b0 + 16 * w;
  float* P0 = LB + w * 1632;             // 16x17
  float* P1 = P0 + 272;
  float* Q  = P0 + 544;                  // 4 x 16x17
  auto storeC = [&](f32x4 a, float* Buf) {
#pragma unroll
    for (int r = 0; r < 4; ++r) Buf[m * 17 + g * 4 + r] = a[r];
  };

#pragma unroll
  for (int h = 0; h < 4; ++h) {          // L4 nodes 2h,2h+1 -> L5 node h
    f32x4 a0 = mfma_core<8, false>(&s1r[(size_t)(64 * h) * BTOT + m],
                                   &s1r[(size_t)(64 * h + 16) * BTOT + m],
                                   BTOT, U + OFF4 + (size_t)(2 * h) * 8192, lane);
    storeC(a0, P0);
    f32x4 a1 = mfma_core<8, false>(&s1r[(size_t)(64 * h + 32) * BTOT + m],
                                   &s1r[(size_t)(64 * h + 48) * BTOT + m],
                                   BTOT, U + OFF4 + (size_t)(2 * h + 1) * 8192, lane);
    storeC(a1, P1);
    f32x4 a5 = mfma_core<8, false>(&P0[m], &P1[m], 17,
                                   U + OFF5 + (size_t)h * 8192, lane);
    storeC(a5, Q + h * 272);
  }
  f32x4 a60 = mfma_core<8, false>(&Q[m], &Q[272 + m], 17, U + OFF6, lane);
  storeC(a60, P0);
  f32x4 a61 = mfma_core<8, false>(&Q[544 + m], &Q[816 + m], 17,
                                  U + OFF6 + 8192, lane);
  storeC(a61, P1);
  f32x4 a7 = mfma_core<8, false>(&P0[m], &P1[m], 17, U + OFF7, lane);
  if (m == 0) {
#pragma unroll
    for (int r = 0; r < 4; ++r) out[b0 + 16 * w + g * 4 + r] = a7[r];
  }
}

extern "C" void kernel_launch(void* const* d_in, const int* in_sizes, int n_in,
                              void* d_out, int out_size, void* d_ws, size_t ws_size,
                              hipStream_t stream) {
  const float* x    = (const float*)d_in[0];
  const float* fmin = (const float*)d_in[1];
  const float* W0   = (const float*)d_in[2];
  const float* W1   = (const float*)d_in[3];
  const float* W2   = (const float*)d_in[4];
  const float* W3   = (const float*)d_in[5];
  const float* W4   = (const float*)d_in[6];
  const float* W5   = (const float*)d_in[7];
  const float* W6   = (const float*)d_in[8];
  const float* W7   = (const float*)d_in[9];
  float* out = (float*)d_out;

  // ws: [0,4MB) W-frags U | [4MB,+16.8MB) s1 | cnt[256]
  ushort* U = (ushort*)d_ws;
  float* s1 = (float*)((char*)d_ws + (4u << 20));
  uint* cnt = (uint*)((char*)d_ws + (4u << 20) + (size_t)16 * 16 * BTOT * 4);

  wprep_kernel<<<255, 256, 0, stream>>>(W0, W1, W2, W3, W4, W5, W6, W7, U, cnt);
  ttn_fused_kernel<<<dim3(256, 16), 256, 0, stream>>>(x, fmin, U, s1, cnt, out);
}

// Round 15
// 248.126 us; speedup vs baseline: 2.4716x; 2.4716x over previous
//
#include <hip/hip_runtime.h>
#include <math.h>

#define BTOT 16384

typedef __attribute__((ext_vector_type(8))) short s16x8;
typedef __attribute__((ext_vector_type(4))) float f32x4;
typedef __attribute__((ext_vector_type(4))) uint u32x4;
typedef __attribute__((ext_vector_type(2))) float f32x2;
typedef __attribute__((ext_vector_type(2))) uint u32x2;

// U region offsets (in ushorts). Per-node blob: [KTN*512 hi][KTN*512 lo].
#define OFF0 0u          // W0: 128 nodes x 5120
#define OFF1 655360u     // W1: 64 x 8192
#define OFF2 1179648u    // W2: 32 x 8192
#define OFF3 1441792u    // W3: 16 x 8192
#define OFF4 1572864u    // W4: 8 x 8192
#define OFF5 1638400u    // W5: 4 x 8192
#define OFF6 1671168u    // W6: 2 x 8192
#define OFF7 1687552u    // W7: 1 x 8192

__device__ __forceinline__ ushort rtn_bf16(float x) {
  uint u = __builtin_bit_cast(uint, x);
  uint r = u + 0x7fffu + ((u >> 16) & 1u);
  return (ushort)(r >> 16);
}

// ---------------- W-frag prep: LDS-staged coalesced reads ----------------------
__global__ __launch_bounds__(256) void wprep_kernel(
    const float* __restrict__ W0, const float* __restrict__ W1,
    const float* __restrict__ W2, const float* __restrict__ W3,
    const float* __restrict__ W4, const float* __restrict__ W5,
    const float* __restrict__ W6, const float* __restrict__ W7,
    ushort* __restrict__ U) {
  __shared__ float WL[4096];
  int blk = blockIdx.x;
  const float* Wsrc; ushort* dst; int ktN, din, nsrc; bool dout1 = false;
  if (blk < 128)      { Wsrc = W0 + blk * 1296;         dst = U + OFF0 + (size_t)blk * 5120;         ktN = 5; din = 9;  nsrc = 1296; }
  else if (blk < 192) { Wsrc = W1 + (blk - 128) * 4096; dst = U + OFF1 + (size_t)(blk - 128) * 8192; ktN = 8; din = 16; nsrc = 4096; }
  else if (blk < 224) { Wsrc = W2 + (blk - 192) * 4096; dst = U + OFF2 + (size_t)(blk - 192) * 8192; ktN = 8; din = 16; nsrc = 4096; }
  else if (blk < 240) { Wsrc = W3 + (blk - 224) * 4096; dst = U + OFF3 + (size_t)(blk - 224) * 8192; ktN = 8; din = 16; nsrc = 4096; }
  else if (blk < 248) { Wsrc = W4 + (blk - 240) * 4096; dst = U + OFF4 + (size_t)(blk - 240) * 8192; ktN = 8; din = 16; nsrc = 4096; }
  else if (blk < 252) { Wsrc = W5 + (blk - 248) * 4096; dst = U + OFF5 + (size_t)(blk - 248) * 8192; ktN = 8; din = 16; nsrc = 4096; }
  else if (blk < 254) { Wsrc = W6 + (blk - 252) * 4096; dst = U + OFF6 + (size_t)(blk - 252) * 8192; ktN = 8; din = 16; nsrc = 4096; }
  else                { Wsrc = W7;                      dst = U + OFF7;                              ktN = 8; din = 16; nsrc = 256; dout1 = true; }
  for (int i = threadIdx.x; i < nsrc; i += 256) WL[i] = Wsrc[i];   // coalesced
  __syncthreads();
  int entries = ktN * 512;
  for (int e = threadIdx.x; e < entries; e += 256) {
    int kt = e >> 9, l = (e >> 3) & 63, jv = e & 7;
    int k = kt * 32 + ((l >> 4) << 3) + jv;
    int i = k >> 4, j = k & 15, n = l & 15;
    float w;
    if (dout1) w = (n == 0) ? WL[i * 16 + j] : 0.f;
    else       w = (i < din && j < din) ? WL[(i * din + j) * 16 + n] : 0.f;
    uint u = __builtin_bit_cast(uint, w);
    uint h = u & 0xffff0000u;
    dst[e] = (ushort)(h >> 16);
    dst[entries + e] = rtn_bf16(w - __builtin_bit_cast(float, h));
  }
}

// ---- split + 3 MFMAs for one 16-b tile, given resident wh/wl ------------------
__device__ __forceinline__ f32x4 split3(float li, const f32x2* rf2,
                                        s16x8 wh, s16x8 wl, f32x4 acc) {
  const f32x2 li2 = {li, li};
  u32x4 hv, lv;
#pragma unroll
  for (int jp = 0; jp < 4; ++jp) {
    f32x2 p2 = li2 * rf2[jp];
    u32x2 u2 = __builtin_bit_cast(u32x2, p2);
    u32x2 hb = u2 & 0xffff0000u;
    f32x2 h2 = __builtin_bit_cast(f32x2, hb);
    f32x2 q2 = __builtin_elementwise_fma(li2, rf2[jp], -h2);
    u32x2 uq = __builtin_bit_cast(u32x2, q2);
    hv[jp] = __builtin_amdgcn_perm(u2.y, u2.x, 0x07060302u);
    lv[jp] = __builtin_amdgcn_perm(uq.y, uq.x, 0x07060302u);
  }
  s16x8 ahi = __builtin_bit_cast(s16x8, hv);
  s16x8 alo = __builtin_bit_cast(s16x8, lv);
  acc = __builtin_amdgcn_mfma_f32_16x16x32_bf16(ahi, wh, acc, 0, 0, 0);
  acc = __builtin_amdgcn_mfma_f32_16x16x32_bf16(alo, wh, acc, 0, 0, 0);
  acc = __builtin_amdgcn_mfma_f32_16x16x32_bf16(ahi, wl, acc, 0, 0, 0);
  return acc;
}

// ---------------- single-tile MFMA bilinear core (verified) --------------------
// L0M: 9-dim level-0 inputs, rows >=9 read as zero (predicated; no pad row).
template <int KTN, bool L0M>
__device__ __forceinline__ f32x4 mfma_core(const float* Lcol, const float* Rcol,
                                           const int ld, const ushort* __restrict__ Wf,
                                           int lane) {
  const int g = lane >> 4;
  const int j0 = (g & 1) * 8, gh = g >> 1;
  const float* Lg = Lcol + gh * ld;
  float lf[KTN];
#pragma unroll
  for (int i = 0; i < KTN; ++i)
    lf[i] = (L0M && (2 * i + gh > 8)) ? 0.f : Lg[2 * i * ld];
  f32x2 rf2[4];
#pragma unroll
  for (int j = 0; j < 8; ++j) {
    float v = (L0M && (j0 + j >= 9)) ? 0.f : Rcol[(j0 + j) * ld];
    rf2[j >> 1][j & 1] = v;
  }
  f32x4 acc = {0.f, 0.f, 0.f, 0.f};
  const int entries = KTN * 512;
#pragma unroll
  for (int kt = 0; kt < KTN; ++kt) {
    const s16x8 wh = *(const s16x8*)&Wf[(kt * 64 + lane) * 8];
    const s16x8 wl = *(const s16x8*)&Wf[entries + (kt * 64 + lane) * 8];
    acc = split3(lf[kt], rf2, wh, wl, acc);
  }
  return acc;
}

#define LDF 67   // front leading dim: 67 % 32 = 3 -> <=2-way LDS conflicts (free)

__device__ __forceinline__ void feats_col(float xv, float* Fb, int col) {
  float s1 = __sinf(xv), c1 = __cosf(xv);
  Fb[0 * LDF + col] = 1.f; Fb[1 * LDF + col] = s1; Fb[5 * LDF + col] = c1;
  float sk = s1, ck = c1;
#pragma unroll
  for (int k = 2; k <= 4; ++k) {
    float sn = s1 * ck + c1 * sk, cn = c1 * ck - s1 * sk;
    sk = sn; ck = cn;
    Fb[k * LDF + col] = sk; Fb[(4 + k) * LDF + col] = ck;
  }
}

// ---------------- Levels 0-3 fused, zero-barrier (best measured shape) ---------
// s1 stores NON-TEMPORAL: written once, read once by cross-XCD consumers;
// keep them out of local L2 (route via shared L3) and stop evicting U frags.
__global__ __launch_bounds__(256, 4) void ttn_front_kernel(
    const float* __restrict__ x, const float* __restrict__ fminp,
    const ushort* __restrict__ U, float* __restrict__ s1out) {
  __shared__ float F0[9 * LDF], F1[9 * LDF];
  __shared__ float A0[16 * LDF], B0[16 * LDF];
  __shared__ float A1[16 * LDF], B1[16 * LDF];
  __shared__ float A2[16 * LDF], B2[16 * LDF];

  const int tid = threadIdx.x;
  const int lane = tid & 63, w = tid >> 6;
  const int m = lane & 15, g = lane >> 4;
  const int bl = w * 16 + m;
  const int b0 = blockIdx.x * 64;
  const int s = blockIdx.y;
  const float fmin = fminp[0];

  const float* xw = x + (size_t)(b0 + w * 16 + (lane & 15)) * 256 + s * 16;
  float* outG = s1out + (size_t)(s * 16) * BTOT + b0;

  auto storeL = [&](f32x4 a, float* Out) {
#pragma unroll
    for (int r = 0; r < 4; ++r) Out[m * LDF + w * 16 + g * 4 + r] = a[r];
  };

  for (int t = 0; t < 8; ++t) {
    if (lane < 32) {
      int side = lane >> 4;
      float xv = xw[2 * t + side] * fmin;
      feats_col(xv, side ? F1 : F0, w * 16 + (lane & 15));
    }
    f32x4 a = mfma_core<5, true>(&F0[bl], &F1[bl], LDF,
                                 U + OFF0 + (size_t)(8 * s + t) * 5120, lane);
    storeL(a, (t & 1) ? B0 : A0);
    if (t & 1) {
      f32x4 c1 = mfma_core<8, false>(&A0[bl], &B0[bl], LDF,
                                     U + OFF1 + (size_t)(4 * s + (t >> 1)) * 8192, lane);
      storeL(c1, ((t >> 1) & 1) ? B1 : A1);
      if ((t & 3) == 3) {
        f32x4 c2 = mfma_core<8, false>(&A1[bl], &B1[bl], LDF,
                                       U + OFF2 + (size_t)(2 * s + (t >> 2)) * 8192, lane);
        storeL(c2, ((t >> 2) & 1) ? B2 : A2);
        if (t == 7) {
          f32x4 c3 = mfma_core<8, false>(&A2[bl], &B2[bl], LDF,
                                         U + OFF3 + (size_t)s * 8192, lane);
#pragma unroll
          for (int r = 0; r < 4; ++r)
            __builtin_nontemporal_store(c3[r],
                &outG[(size_t)m * BTOT + w * 16 + g * 4 + r]);
        }
      }
    }
  }
}

// ---------------- Levels 4-7: tree-parallel, 8 waves / 16-b tile ---------------
// Wave v: L4 node v; barrier; waves 0-3: L5; barrier; 0-1: L6; barrier; 0: L7.
// s1 staging loads NON-TEMPORAL (read-once, cross-XCD) via ext-vector f32x4
// (HIP float4 is a struct -> invalid operand for the builtin).
__global__ __launch_bounds__(512) void ttn_back_kernel(
    const float* __restrict__ s1, const ushort* __restrict__ U,
    float* __restrict__ out) {
  __shared__ float T[256 * 17];        // 17.4 KB
  __shared__ float P[8][16 * 17];      // 8.7 KB
  const int tid = threadIdx.x;
  const int lane = tid & 63, v = tid >> 6;   // v = 0..7
  const int m = lane & 15, g = lane >> 4;
  const int b0 = blockIdx.x * 16;

  auto storeC = [&](f32x4 a, float* Buf) {
#pragma unroll
    for (int r = 0; r < 4; ++r) Buf[m * 17 + g * 4 + r] = a[r];
  };

#pragma unroll
  for (int it = 0; it < 2; ++it) {     // stage [256 rows][16 b], coalesced 16B
    int idx = it * 512 + tid;          // 0..1023
    int r = idx >> 2, c4 = (idx & 3) * 4;
    f32x4 vv = __builtin_nontemporal_load(
        (const f32x4*)&s1[(size_t)r * BTOT + b0 + c4]);
    T[r * 17 + c4 + 0] = vv.x; T[r * 17 + c4 + 1] = vv.y;
    T[r * 17 + c4 + 2] = vv.z; T[r * 17 + c4 + 3] = vv.w;
  }
  __syncthreads();

  // L4 node v: rows 32v..+15 x 32v+16..+31 -> P[v]
  {
    f32x4 a = mfma_core<8, false>(&T[(32 * v) * 17 + m], &T[(32 * v + 16) * 17 + m],
                                  17, U + OFF4 + (size_t)v * 8192, lane);
    storeC(a, P[v]);
  }
  __syncthreads();

  if (v < 4) {  // L5 node v: P[2v] x P[2v+1] -> T region v (T dead)
    f32x4 a = mfma_core<8, false>(&P[2 * v][m], &P[2 * v + 1][m], 17,
                                  U + OFF5 + (size_t)v * 8192, lane);
    storeC(a, &T[v * 16 * 17]);
  }
  __syncthreads();

  if (v < 2) {  // L6 node v: Tq[2v] x Tq[2v+1] -> P[v] (P dead)
    f32x4 a = mfma_core<8, false>(&T[(2 * v) * 16 * 17 + m],
                                  &T[(2 * v + 1) * 16 * 17 + m], 17,
                                  U + OFF6 + (size_t)v * 8192, lane);
    storeC(a, P[v]);
  }
  __syncthreads();

  if (v == 0) { // L7: P[0] x P[1]; W7-frag nonzero only in d=0 column
    f32x4 a = mfma_core<8, false>(&P[0][m], &P[1][m], 17, U + OFF7, lane);
    if (m == 0) {
#pragma unroll
      for (int r = 0; r < 4; ++r) out[b0 + g * 4 + r] = a[r];
    }
  }
}

extern "C" void kernel_launch(void* const* d_in, const int* in_sizes, int n_in,
                              void* d_out, int out_size, void* d_ws, size_t ws_size,
                              hipStream_t stream) {
  const float* x    = (const float*)d_in[0];
  const float* fmin = (const float*)d_in[1];
  const float* W0   = (const float*)d_in[2];
  const float* W1   = (const float*)d_in[3];
  const float* W2   = (const float*)d_in[4];
  const float* W3   = (const float*)d_in[5];
  const float* W4   = (const float*)d_in[6];
  const float* W5   = (const float*)d_in[7];
  const float* W6   = (const float*)d_in[8];
  const float* W7   = (const float*)d_in[9];
  float* out = (float*)d_out;

  // ws: [0,4MB) W-frags U | [4MB,+16.8MB) s1
  ushort* U = (ushort*)d_ws;
  float* s1 = (float*)((char*)d_ws + (4u << 20));

  wprep_kernel<<<255, 256, 0, stream>>>(W0, W1, W2, W3, W4, W5, W6, W7, U);
  ttn_front_kernel<<<dim3(256, 16), 256, 0, stream>>>(x, fmin, U, s1);
  ttn_back_kernel<<<1024, 512, 0, stream>>>(s1, U, out);
}

// Round 16
// 235.399 us; speedup vs baseline: 2.6052x; 1.0541x over previous
//
#include <hip/hip_runtime.h>
#include <math.h>

#define BTOT 16384

typedef __attribute__((ext_vector_type(8))) short s16x8;
typedef __attribute__((ext_vector_type(4))) float f32x4;
typedef __attribute__((ext_vector_type(4))) uint u32x4;
typedef __attribute__((ext_vector_type(2))) float f32x2;
typedef __attribute__((ext_vector_type(2))) uint u32x2;

// U region offsets (in ushorts). Per-node blob: [KTN*512 hi][KTN*512 lo].
#define OFF0 0u          // W0: 128 nodes x 5120
#define OFF1 655360u     // W1: 64 x 8192
#define OFF2 1179648u    // W2: 32 x 8192
#define OFF3 1441792u    // W3: 16 x 8192
#define OFF4 1572864u    // W4: 8 x 8192
#define OFF5 1638400u    // W5: 4 x 8192
#define OFF6 1671168u    // W6: 2 x 8192
#define OFF7 1687552u    // W7: 1 x 8192

__device__ __forceinline__ ushort rtn_bf16(float x) {
  uint u = __builtin_bit_cast(uint, x);
  uint r = u + 0x7fffu + ((u >> 16) & 1u);
  return (ushort)(r >> 16);
}

// ---------------- W-frag prep: LDS-staged coalesced reads ----------------------
__global__ __launch_bounds__(256) void wprep_kernel(
    const float* __restrict__ W0, const float* __restrict__ W1,
    const float* __restrict__ W2, const float* __restrict__ W3,
    const float* __restrict__ W4, const float* __restrict__ W5,
    const float* __restrict__ W6, const float* __restrict__ W7,
    ushort* __restrict__ U) {
  __shared__ float WL[4096];
  int blk = blockIdx.x;
  const float* Wsrc; ushort* dst; int ktN, din, nsrc; bool dout1 = false;
  if (blk < 128)      { Wsrc = W0 + blk * 1296;         dst = U + OFF0 + (size_t)blk * 5120;         ktN = 5; din = 9;  nsrc = 1296; }
  else if (blk < 192) { Wsrc = W1 + (blk - 128) * 4096; dst = U + OFF1 + (size_t)(blk - 128) * 8192; ktN = 8; din = 16; nsrc = 4096; }
  else if (blk < 224) { Wsrc = W2 + (blk - 192) * 4096; dst = U + OFF2 + (size_t)(blk - 192) * 8192; ktN = 8; din = 16; nsrc = 4096; }
  else if (blk < 240) { Wsrc = W3 + (blk - 224) * 4096; dst = U + OFF3 + (size_t)(blk - 224) * 8192; ktN = 8; din = 16; nsrc = 4096; }
  else if (blk < 248) { Wsrc = W4 + (blk - 240) * 4096; dst = U + OFF4 + (size_t)(blk - 240) * 8192; ktN = 8; din = 16; nsrc = 4096; }
  else if (blk < 252) { Wsrc = W5 + (blk - 248) * 4096; dst = U + OFF5 + (size_t)(blk - 248) * 8192; ktN = 8; din = 16; nsrc = 4096; }
  else if (blk < 254) { Wsrc = W6 + (blk - 252) * 4096; dst = U + OFF6 + (size_t)(blk - 252) * 8192; ktN = 8; din = 16; nsrc = 4096; }
  else                { Wsrc = W7;                      dst = U + OFF7;                              ktN = 8; din = 16; nsrc = 256; dout1 = true; }
  for (int i = threadIdx.x; i < nsrc; i += 256) WL[i] = Wsrc[i];   // coalesced
  __syncthreads();
  int entries = ktN * 512;
  for (int e = threadIdx.x; e < entries; e += 256) {
    int kt = e >> 9, l = (e >> 3) & 63, jv = e & 7;
    int k = kt * 32 + ((l >> 4) << 3) + jv;
    int i = k >> 4, j = k & 15, n = l & 15;
    float w;
    if (dout1) w = (n == 0) ? WL[i * 16 + j] : 0.f;
    else       w = (i < din && j < din) ? WL[(i * din + j) * 16 + n] : 0.f;
    uint u = __builtin_bit_cast(uint, w);
    uint h = u & 0xffff0000u;
    dst[e] = (ushort)(h >> 16);
    dst[entries + e] = rtn_bf16(w - __builtin_bit_cast(float, h));
  }
}

// ---- split + 3 MFMAs for one 16-b tile, given resident wh/wl ------------------
__device__ __forceinline__ f32x4 split3(float li, const f32x2* rf2,
                                        s16x8 wh, s16x8 wl, f32x4 acc) {
  const f32x2 li2 = {li, li};
  u32x4 hv, lv;
#pragma unroll
  for (int jp = 0; jp < 4; ++jp) {
    f32x2 p2 = li2 * rf2[jp];
    u32x2 u2 = __builtin_bit_cast(u32x2, p2);
    u32x2 hb = u2 & 0xffff0000u;
    f32x2 h2 = __builtin_bit_cast(f32x2, hb);
    f32x2 q2 = __builtin_elementwise_fma(li2, rf2[jp], -h2);
    u32x2 uq = __builtin_bit_cast(u32x2, q2);
    hv[jp] = __builtin_amdgcn_perm(u2.y, u2.x, 0x07060302u);
    lv[jp] = __builtin_amdgcn_perm(uq.y, uq.x, 0x07060302u);
  }
  s16x8 ahi = __builtin_bit_cast(s16x8, hv);
  s16x8 alo = __builtin_bit_cast(s16x8, lv);
  acc = __builtin_amdgcn_mfma_f32_16x16x32_bf16(ahi, wh, acc, 0, 0, 0);
  acc = __builtin_amdgcn_mfma_f32_16x16x32_bf16(alo, wh, acc, 0, 0, 0);
  acc = __builtin_amdgcn_mfma_f32_16x16x32_bf16(ahi, wl, acc, 0, 0, 0);
  return acc;
}

// ---------------- single-tile MFMA bilinear core (verified) --------------------
// L0M: 9-dim level-0 inputs, rows >=9 read as zero (predicated; no pad row).
template <int KTN, bool L0M>
__device__ __forceinline__ f32x4 mfma_core(const float* Lcol, const float* Rcol,
                                           const int ld, const ushort* __restrict__ Wf,
                                           int lane) {
  const int g = lane >> 4;
  const int j0 = (g & 1) * 8, gh = g >> 1;
  const float* Lg = Lcol + gh * ld;
  float lf[KTN];
#pragma unroll
  for (int i = 0; i < KTN; ++i)
    lf[i] = (L0M && (2 * i + gh > 8)) ? 0.f : Lg[2 * i * ld];
  f32x2 rf2[4];
#pragma unroll
  for (int j = 0; j < 8; ++j) {
    float v = (L0M && (j0 + j >= 9)) ? 0.f : Rcol[(j0 + j) * ld];
    rf2[j >> 1][j & 1] = v;
  }
  f32x4 acc = {0.f, 0.f, 0.f, 0.f};
  const int entries = KTN * 512;
#pragma unroll
  for (int kt = 0; kt < KTN; ++kt) {
    const s16x8 wh = *(const s16x8*)&Wf[(kt * 64 + lane) * 8];
    const s16x8 wl = *(const s16x8*)&Wf[entries + (kt * 64 + lane) * 8];
    acc = split3(lf[kt], rf2, wh, wl, acc);
  }
  return acc;
}

#define LDF 67   // front leading dim: 67 % 32 = 3 -> <=2-way LDS conflicts (free)

__device__ __forceinline__ void feats_col(float xv, float* Fb, int col) {
  float s1 = __sinf(xv), c1 = __cosf(xv);
  Fb[0 * LDF + col] = 1.f; Fb[1 * LDF + col] = s1; Fb[5 * LDF + col] = c1;
  float sk = s1, ck = c1;
#pragma unroll
  for (int k = 2; k <= 4; ++k) {
    float sn = s1 * ck + c1 * sk, cn = c1 * ck - s1 * sk;
    sk = sn; ck = cn;
    Fb[k * LDF + col] = sk; Fb[(4 + k) * LDF + col] = ck;
  }
}

// ---------------- Levels 0-3 fused, zero-barrier (best measured shape) ---------
__global__ __launch_bounds__(256, 4) void ttn_front_kernel(
    const float* __restrict__ x, const float* __restrict__ fminp,
    const ushort* __restrict__ U, float* __restrict__ s1out) {
  __shared__ float F0[9 * LDF], F1[9 * LDF];
  __shared__ float A0[16 * LDF], B0[16 * LDF];
  __shared__ float A1[16 * LDF], B1[16 * LDF];
  __shared__ float A2[16 * LDF], B2[16 * LDF];

  const int tid = threadIdx.x;
  const int lane = tid & 63, w = tid >> 6;
  const int m = lane & 15, g = lane >> 4;
  const int bl = w * 16 + m;
  const int b0 = blockIdx.x * 64;
  const int s = blockIdx.y;
  const float fmin = fminp[0];

  const float* xw = x + (size_t)(b0 + w * 16 + (lane & 15)) * 256 + s * 16;
  float* outG = s1out + (size_t)(s * 16) * BTOT + b0;

  auto storeL = [&](f32x4 a, float* Out) {
#pragma unroll
    for (int r = 0; r < 4; ++r) Out[m * LDF + w * 16 + g * 4 + r] = a[r];
  };

  for (int t = 0; t < 8; ++t) {
    if (lane < 32) {
      int side = lane >> 4;
      float xv = xw[2 * t + side] * fmin;
      feats_col(xv, side ? F1 : F0, w * 16 + (lane & 15));
    }
    f32x4 a = mfma_core<5, true>(&F0[bl], &F1[bl], LDF,
                                 U + OFF0 + (size_t)(8 * s + t) * 5120, lane);
    storeL(a, (t & 1) ? B0 : A0);
    if (t & 1) {
      f32x4 c1 = mfma_core<8, false>(&A0[bl], &B0[bl], LDF,
                                     U + OFF1 + (size_t)(4 * s + (t >> 1)) * 8192, lane);
      storeL(c1, ((t >> 1) & 1) ? B1 : A1);
      if ((t & 3) == 3) {
        f32x4 c2 = mfma_core<8, false>(&A1[bl], &B1[bl], LDF,
                                       U + OFF2 + (size_t)(2 * s + (t >> 2)) * 8192, lane);
        storeL(c2, ((t >> 2) & 1) ? B2 : A2);
        if (t == 7) {
          f32x4 c3 = mfma_core<8, false>(&A2[bl], &B2[bl], LDF,
                                         U + OFF3 + (size_t)s * 8192, lane);
#pragma unroll
          for (int r = 0; r < 4; ++r)
            outG[(size_t)m * BTOT + w * 16 + g * 4 + r] = c3[r];
        }
      }
    }
  }
}

// ---------------- Levels 4-7: tree-parallel, 8 waves / 16-b tile ---------------
// Wave v: L4 node v; barrier; waves 0-3: L5; barrier; 0-1: L6; barrier; 0: L7.
__global__ __launch_bounds__(512) void ttn_back_kernel(
    const float* __restrict__ s1, const ushort* __restrict__ U,
    float* __restrict__ out) {
  __shared__ float T[256 * 17];        // 17.4 KB
  __shared__ float P[8][16 * 17];      // 8.7 KB
  const int tid = threadIdx.x;
  const int lane = tid & 63, v = tid >> 6;   // v = 0..7
  const int m = lane & 15, g = lane >> 4;
  const int b0 = blockIdx.x * 16;

  auto storeC = [&](f32x4 a, float* Buf) {
#pragma unroll
    for (int r = 0; r < 4; ++r) Buf[m * 17 + g * 4 + r] = a[r];
  };

#pragma unroll
  for (int it = 0; it < 2; ++it) {     // stage [256 rows][16 b], coalesced float4
    int idx = it * 512 + tid;          // 0..1023
    int r = idx >> 2, c4 = (idx & 3) * 4;
    float4 vv = *(const float4*)&s1[(size_t)r * BTOT + b0 + c4];
    T[r * 17 + c4 + 0] = vv.x; T[r * 17 + c4 + 1] = vv.y;
    T[r * 17 + c4 + 2] = vv.z; T[r * 17 + c4 + 3] = vv.w;
  }
  __syncthreads();

  // L4 node v: rows 32v..+15 x 32v+16..+31 -> P[v]
  {
    f32x4 a = mfma_core<8, false>(&T[(32 * v) * 17 + m], &T[(32 * v + 16) * 17 + m],
                                  17, U + OFF4 + (size_t)v * 8192, lane);
    storeC(a, P[v]);
  }
  __syncthreads();

  if (v < 4) {  // L5 node v: P[2v] x P[2v+1] -> T region v (T dead)
    f32x4 a = mfma_core<8, false>(&P[2 * v][m], &P[2 * v + 1][m], 17,
                                  U + OFF5 + (size_t)v * 8192, lane);
    storeC(a, &T[v * 16 * 17]);
  }
  __syncthreads();

  if (v < 2) {  // L6 node v: Tq[2v] x Tq[2v+1] -> P[v] (P dead)
    f32x4 a = mfma_core<8, false>(&T[(2 * v) * 16 * 17 + m],
                                  &T[(2 * v + 1) * 16 * 17 + m], 17,
                                  U + OFF6 + (size_t)v * 8192, lane);
    storeC(a, P[v]);
  }
  __syncthreads();

  if (v == 0) { // L7: P[0] x P[1]; W7-frag nonzero only in d=0 column
    f32x4 a = mfma_core<8, false>(&P[0][m], &P[1][m], 17, U + OFF7, lane);
    if (m == 0) {
#pragma unroll
      for (int r = 0; r < 4; ++r) out[b0 + g * 4 + r] = a[r];
    }
  }
}

extern "C" void kernel_launch(void* const* d_in, const int* in_sizes, int n_in,
                              void* d_out, int out_size, void* d_ws, size_t ws_size,
                              hipStream_t stream) {
  const float* x    = (const float*)d_in[0];
  const float* fmin = (const float*)d_in[1];
  const float* W0   = (const float*)d_in[2];
  const float* W1   = (const float*)d_in[3];
  const float* W2   = (const float*)d_in[4];
  const float* W3   = (const float*)d_in[5];
  const float* W4   = (const float*)d_in[6];
  const float* W5   = (const float*)d_in[7];
  const float* W6   = (const float*)d_in[8];
  const float* W7   = (const float*)d_in[9];
  float* out = (float*)d_out;

  // ws: [0,4MB) W-frags U | [4MB,+16.8MB) s1
  ushort* U = (ushort*)d_ws;
  float* s1 = (float*)((char*)d_ws + (4u << 20));

  wprep_kernel<<<255, 256, 0, stream>>>(W0, W1, W2, W3, W4, W5, W6, W7, U);
  ttn_front_kernel<<<dim3(256, 16), 256, 0, stream>>>(x, fmin, U, s1);
  ttn_back_kernel<<<1024, 512, 0, stream>>>(s1, U, out);
}